// Round 6
// baseline (223.502 us; speedup 1.0000x reference)
//
#include <hip/hip_runtime.h>

#define NB 4
#define P 1024
#define ITERS 50
#define WPB 32              // workgroups per batch
#define THREADS 512
#define WAVES 8
#define K_COEF (-14.426950408889634f)  // -log2(e)/eps, eps=0.1
#define DELTA 1e-8f
#define SCALE 274877906944.0f          // 2^38 fixed-point scale
#define M56 0x00FFFFFFFFFFFFFFull
#define CNT_ONE (1ull << 56)

typedef unsigned long long u64;
typedef unsigned int u32;

// ws layout: [0, 1.6MB) z[NB][ITERS][P] u64 : (arrivals<<56) | fixed-point sum

__global__ void sink_zero(u64* z, float* out) {
    size_t t = (size_t)blockIdx.x * 1024 + threadIdx.x;
    if (t < (size_t)NB * ITERS * P) z[t] = 0ull;
    if (t < NB) out[t] = 0.0f;
}

__global__ __launch_bounds__(THREADS, 2)
void sink_main(const float* __restrict__ mu, const float* __restrict__ nu,
               const float* __restrict__ C, float* __restrict__ out,
               u64* __restrict__ z) {
    const int n   = blockIdx.x >> 5;   // batch
    const int w   = blockIdx.x & 31;   // wg within batch
    const int tid = threadIdx.x;
    const int wq  = tid >> 6;          // wave 0..7
    const int l   = tid & 63;          // lane

    u64* zb = z + (size_t)n * ITERS * P;
    const float* Cb = C + (size_t)n * P * P;
    const int base = w * 32 + wq * 4;  // this wave's first row

    float Kr[4][16], muv[4], b_r[16], a_own[4];

    // Kr[q][k] = K[base+q][l+64k]  (each load: 64 lanes x 4B = 256B coalesced)
    #pragma unroll
    for (int q = 0; q < 4; ++q) {
        const int r = base + q;
        #pragma unroll
        for (int k = 0; k < 16; ++k)
            Kr[q][k] = exp2f(K_COEF * Cb[(size_t)r * P + l + 64 * k]);
        muv[q] = mu[n * P + r] + DELTA;
    }
    // this thread's two columns: tid and tid+512
    const float nuv0 = (nu[n * P + tid] + DELTA) * SCALE;
    const float nuv1 = (nu[n * P + tid + 512] + DELTA) * SCALE;

    __shared__ float bs[P];            // 4KB  : broadcast b
    __shared__ float zs[WAVES][P];     // 32KB : per-wave column partials

    #pragma unroll
    for (int k = 0; k < 16; ++k) b_r[k] = 1.0f;   // v=0 -> b=1

    for (int t = 0; t < ITERS; ++t) {
        // a_i = (mu_i+d) / sum_j K_ij b_j   (own rows, never published)
        #pragma unroll
        for (int q = 0; q < 4; ++q) {
            float y = 0.f;
            #pragma unroll
            for (int k = 0; k < 16; ++k) y += Kr[q][k] * b_r[k];
            #pragma unroll
            for (int off = 32; off > 0; off >>= 1) y += __shfl_xor(y, off, 64);
            a_own[q] = muv[q] / y;
        }
        // per-wave column partials
        #pragma unroll
        for (int k = 0; k < 16; ++k)
            zs[wq][l + 64 * k] = Kr[0][k] * a_own[0] + Kr[1][k] * a_own[1]
                               + Kr[2][k] * a_own[2] + Kr[3][k] * a_own[3];
        __syncthreads();
        // WG reduce (8 waves) -> ONE tagged fixed-point RMW per column per WG
        float red0 = 0.f, red1 = 0.f;
        #pragma unroll
        for (int g = 0; g < WAVES; ++g) {
            red0 += zs[g][tid];
            red1 += zs[g][tid + 512];
        }
        u64* zt = zb + (size_t)t * P;
        const u64 own0 = CNT_ONE + (u64)(red0 * SCALE);
        const u64 own1 = CNT_ONE + (u64)(red1 * SCALE);
        u64 v0 = __hip_atomic_fetch_add(&zt[tid], own0, __ATOMIC_RELAXED,
                                        __HIP_MEMORY_SCOPE_AGENT) + own0;
        u64 v1 = __hip_atomic_fetch_add(&zt[tid + 512], own1, __ATOMIC_RELAXED,
                                        __HIP_MEMORY_SCOPE_AGENT) + own1;
        // poll own two column words: count in top byte, sum in low 56 bits
        while (((v0 >> 56) != (u64)WPB) | ((v1 >> 56) != (u64)WPB)) {
            __builtin_amdgcn_s_sleep(1);
            if ((v0 >> 56) != (u64)WPB)
                v0 = __hip_atomic_load(&zt[tid], __ATOMIC_RELAXED,
                                       __HIP_MEMORY_SCOPE_AGENT);
            if ((v1 >> 56) != (u64)WPB)
                v1 = __hip_atomic_load(&zt[tid + 512], __ATOMIC_RELAXED,
                                       __HIP_MEMORY_SCOPE_AGENT);
        }
        bs[tid]       = nuv0 / (float)(v0 & M56);   // b_j = nu_j / z_j
        bs[tid + 512] = nuv1 / (float)(v1 & M56);
        __syncthreads();
        #pragma unroll
        for (int k = 0; k < 16; ++k) b_r[k] = bs[l + 64 * k];
        // no further barrier: poll-pass at t+1 transitively implies all WGs
        // passed this iteration's barriers.
    }

    // fused epilogue: pi = a_i K_ij b_j ; cost = sum pi*C ; copy C through
    float* out_pi = out + 4;
    float* out_C  = out + 4 + (size_t)NB * P * P;
    float costp = 0.f;
    #pragma unroll
    for (int q = 0; q < 4; ++q) {
        const int r = base + q;
        const size_t rowoff = (size_t)n * P * P + (size_t)r * P;
        #pragma unroll
        for (int k = 0; k < 16; ++k) {
            const int j = l + 64 * k;
            const float c = Cb[(size_t)r * P + j];
            const float p = a_own[q] * Kr[q][k] * b_r[k];
            out_pi[rowoff + j] = p;
            out_C[rowoff + j]  = c;
            costp += p * c;
        }
    }
    #pragma unroll
    for (int off = 32; off > 0; off >>= 1) costp += __shfl_xor(costp, off, 64);
    __syncthreads();               // bs free for reuse
    if (l == 0) bs[wq] = costp;
    __syncthreads();
    if (tid == 0) {
        float s = 0.f;
        #pragma unroll
        for (int g = 0; g < WAVES; ++g) s += bs[g];
        atomicAdd(&out[n], s);
    }
}

extern "C" void kernel_launch(void* const* d_in, const int* in_sizes, int n_in,
                              void* d_out, int out_size, void* d_ws, size_t ws_size,
                              hipStream_t stream) {
    const float* mu = (const float*)d_in[0];
    const float* nu = (const float*)d_in[1];
    const float* C  = (const float*)d_in[2];
    float* out = (float*)d_out;
    u64* zws = (u64*)d_ws;   // NB*ITERS*P*8 = 1.6 MB

    sink_zero<<<(NB * ITERS * P + 1023) / 1024, 1024, 0, stream>>>(zws, out);
    sink_main<<<NB * WPB, THREADS, 0, stream>>>(mu, nu, C, out, zws);
}